// Round 1
// baseline (941.451 us; speedup 1.0000x reference)
//
#include <hip/hip_runtime.h>

#define HH 512
#define WW 512
#define NB 4
#define NC 25              // final channel count: 1 + 12*2
#define HWs (HH * WW)

__device__ __forceinline__ int refl(int p, int n) {
    // jnp.pad mode='reflect' (no edge repeat); single reflection valid for |pad| < n
    p = (p < 0) ? -p : p;
    p = (p >= n) ? (2 * n - 2 - p) : p;
    return p;
}

__global__ __launch_bounds__(256) void copy_x_kernel(const float* __restrict__ x,
                                                     float* __restrict__ out) {
    int t = blockIdx.x * 256 + threadIdx.x;   // NB*HWs/4 = 262144 threads
    int b = t >> 16;                          // HWs/4 = 65536 float4 per batch
    int r = t & 65535;
    const float4* src = (const float4*)(x + (size_t)b * HWs);
    float4* dst = (float4*)(out + (size_t)b * NC * HWs);
    dst[r] = src[r];
}

template <int NIN, int DIL>
__global__ __launch_bounds__(256) void msd_layer(const float* __restrict__ wts,
                                                 const float* __restrict__ bias,
                                                 float* __restrict__ buf,
                                                 int layer) {
    int idx = blockIdx.x * 256 + threadIdx.x;   // 262144 threads, 4 px each
    int g = idx & 127;                          // column group (W/4 = 128)
    int h = (idx >> 7) & 511;
    int b = idx >> 16;
    // h is wave-uniform (64 lanes span 64 column-groups of one row),
    // b is block-uniform -> force into SGPRs so row bases are scalar.
    h = __builtin_amdgcn_readfirstlane(h);
    b = __builtin_amdgcn_readfirstlane(b);
    int w0 = g << 2;

    // Uniform row element offsets (scalar)
    int rowoff[3];
#pragma unroll
    for (int kh = 0; kh < 3; ++kh)
        rowoff[kh] = refl(h + (kh - 1) * DIL, HH) * WW;

    // Per-lane column element offsets, branchless reflect, computed ONCE,
    // reused across all channels and rows.
    int cw[3][4];
#pragma unroll
    for (int kw = 0; kw < 3; ++kw)
#pragma unroll
        for (int j = 0; j < 4; ++j)
            cw[kw][j] = refl(w0 + (kw - 1) * DIL + j, WW);

    float b0 = bias[2 * layer];
    float b1 = bias[2 * layer + 1];
    float a0[4] = {b0, b0, b0, b0};
    float a1[4] = {b1, b1, b1, b1};

    const float* base = buf + (size_t)b * NC * HWs;

    for (int c = 0; c < NIN; ++c) {
        const float* plane = base + (size_t)c * HWs;
        // lane-uniform weight loads -> scalar path
        float wk0[9], wk1[9];
#pragma unroll
        for (int k = 0; k < 9; ++k) {
            wk0[k] = wts[(0 * NIN + c) * 9 + k];
            wk1[k] = wts[(NIN + c) * 9 + k];
        }
#pragma unroll
        for (int kh = 0; kh < 3; ++kh) {
            const float* row = plane + rowoff[kh];
#pragma unroll
            for (int kw = 0; kw < 3; ++kw) {
#pragma unroll
                for (int j = 0; j < 4; ++j) {
                    float v = row[cw[kw][j]];
                    a0[j] = fmaf(v, wk0[kh * 3 + kw], a0[j]);
                    a1[j] = fmaf(v, wk1[kh * 3 + kw], a1[j]);
                }
            }
        }
    }

    size_t opix = (size_t)h * WW + (size_t)w0;
    float* out0 = buf + ((size_t)(b * NC + NIN)) * HWs + opix;
    float* out1 = buf + ((size_t)(b * NC + NIN + 1)) * HWs + opix;
    float4 r0, r1;
    r0.x = fmaxf(a0[0], 0.f); r0.y = fmaxf(a0[1], 0.f);
    r0.z = fmaxf(a0[2], 0.f); r0.w = fmaxf(a0[3], 0.f);
    r1.x = fmaxf(a1[0], 0.f); r1.y = fmaxf(a1[1], 0.f);
    r1.z = fmaxf(a1[2], 0.f); r1.w = fmaxf(a1[3], 0.f);
    *(float4*)out0 = r0;
    *(float4*)out1 = r1;
}

extern "C" void kernel_launch(void* const* d_in, const int* in_sizes, int n_in,
                              void* d_out, int out_size, void* d_ws, size_t ws_size,
                              hipStream_t stream) {
    const float* x = (const float*)d_in[0];
    const float* bias = (const float*)d_in[1];
    float* out = (float*)d_out;

    const int blocks = (NB * HWs / 4) / 256;  // 1024

    copy_x_kernel<<<blocks, 256, 0, stream>>>(x, out);

#define LAYER(i, nin, dil) \
    msd_layer<nin, dil><<<blocks, 256, 0, stream>>>((const float*)d_in[2 + i], bias, out, i)

    LAYER(0, 1, 1);
    LAYER(1, 3, 2);
    LAYER(2, 5, 3);
    LAYER(3, 7, 4);
    LAYER(4, 9, 5);
    LAYER(5, 11, 6);
    LAYER(6, 13, 7);
    LAYER(7, 15, 8);
    LAYER(8, 17, 9);
    LAYER(9, 19, 10);
    LAYER(10, 21, 11);
    LAYER(11, 23, 12);
#undef LAYER
}

// Round 2
// 433.414 us; speedup vs baseline: 2.1722x; 2.1722x over previous
//
#include <hip/hip_runtime.h>

#define HH 512
#define WW 512
#define NB 4
#define NC 25              // final channel count: 1 + 12*2
#define HWs (HH * WW)

__device__ __forceinline__ int refl(int p, int n) {
    // jnp.pad mode='reflect' (no edge repeat); single reflection valid for |pad| < n
    p = (p < 0) ? -p : p;
    p = (p >= n) ? (2 * n - 2 - p) : p;
    return p;
}

__global__ __launch_bounds__(256) void copy_x_kernel(const float* __restrict__ x,
                                                     float* __restrict__ out) {
    int t = blockIdx.x * 256 + threadIdx.x;   // NB*HWs/4 = 262144 threads
    int b = t >> 16;                          // HWs/4 = 65536 float4 per batch
    int r = t & 65535;
    const float4* src = (const float4*)(x + (size_t)b * HWs);
    float4* dst = (float4*)(out + (size_t)b * NC * HWs);
    dst[r] = src[r];
}

// Each thread: 4 vertical pixels (rows h..h+3, one column w), 2 output channels.
// Consecutive lanes -> consecutive columns: every tap load is a coalesced
// 256B contiguous dword load. Row offsets are block-uniform (scalar).
template <int NIN, int DIL>
__global__ __launch_bounds__(256) void msd_layer(const float* __restrict__ wts,
                                                 const float* __restrict__ bias,
                                                 float* __restrict__ buf,
                                                 int layer) {
    int idx = blockIdx.x * 256 + threadIdx.x;   // 262144 threads
    int w = idx & 511;                          // per-lane column
    int strip = __builtin_amdgcn_readfirstlane(idx >> 9);  // block-uniform
    int b = strip >> 7;                         // 128 strips per image
    int h = (strip & 127) << 2;                 // strip base row

    // 12 block-uniform row element-offsets, order [kh][j]
    int rowoff[12];
#pragma unroll
    for (int kh = 0; kh < 3; ++kh)
#pragma unroll
        for (int j = 0; j < 4; ++j)
            rowoff[kh * 4 + j] = refl(h + j + (kh - 1) * DIL, HH) * WW;

    // 3 per-lane reflected column offsets, computed once, reused everywhere
    int cw[3];
#pragma unroll
    for (int kw = 0; kw < 3; ++kw)
        cw[kw] = refl(w + (kw - 1) * DIL, WW);

    float b0 = bias[2 * layer];
    float b1 = bias[2 * layer + 1];
    float a0[4] = {b0, b0, b0, b0};
    float a1[4] = {b1, b1, b1, b1};

    const float* base = buf + (size_t)b * NC * HWs;

    for (int c = 0; c < NIN; ++c) {
        const float* plane = base + (size_t)c * HWs;
        float wk0[9], wk1[9];
#pragma unroll
        for (int k = 0; k < 9; ++k) {
            wk0[k] = wts[c * 9 + k];             // out-ch 0
            wk1[k] = wts[(NIN + c) * 9 + k];     // out-ch 1
        }
#pragma unroll
        for (int kh = 0; kh < 3; ++kh) {
#pragma unroll
            for (int j = 0; j < 4; ++j) {
                const float* row = plane + rowoff[kh * 4 + j];
#pragma unroll
                for (int kw = 0; kw < 3; ++kw) {
                    float v = row[cw[kw]];
                    a0[j] = fmaf(v, wk0[kh * 3 + kw], a0[j]);
                    a1[j] = fmaf(v, wk1[kh * 3 + kw], a1[j]);
                }
            }
        }
    }

    float* out0 = buf + ((size_t)(b * NC + NIN)) * HWs;
    float* out1 = buf + ((size_t)(b * NC + NIN + 1)) * HWs;
#pragma unroll
    for (int j = 0; j < 4; ++j) {
        size_t opix = (size_t)(h + j) * WW + (size_t)w;
        out0[opix] = fmaxf(a0[j], 0.f);
        out1[opix] = fmaxf(a1[j], 0.f);
    }
}

extern "C" void kernel_launch(void* const* d_in, const int* in_sizes, int n_in,
                              void* d_out, int out_size, void* d_ws, size_t ws_size,
                              hipStream_t stream) {
    const float* x = (const float*)d_in[0];
    const float* bias = (const float*)d_in[1];
    float* out = (float*)d_out;

    const int blocks = (NB * HWs / 4) / 256;  // 1024

    copy_x_kernel<<<blocks, 256, 0, stream>>>(x, out);

#define LAYER(i, nin, dil) \
    msd_layer<nin, dil><<<blocks, 256, 0, stream>>>((const float*)d_in[2 + i], bias, out, i)

    LAYER(0, 1, 1);
    LAYER(1, 3, 2);
    LAYER(2, 5, 3);
    LAYER(3, 7, 4);
    LAYER(4, 9, 5);
    LAYER(5, 11, 6);
    LAYER(6, 13, 7);
    LAYER(7, 15, 8);
    LAYER(8, 17, 9);
    LAYER(9, 19, 10);
    LAYER(10, 21, 11);
    LAYER(11, 23, 12);
#undef LAYER
}

// Round 3
// 427.996 us; speedup vs baseline: 2.1997x; 1.0127x over previous
//
#include <hip/hip_runtime.h>

#define HH 512
#define WW 512
#define NB 4
#define NC 25              // final channel count: 1 + 12*2
#define HWs (HH * WW)

__device__ __forceinline__ int refl(int p, int n) {
    // jnp.pad mode='reflect' (no edge repeat); single reflection valid for |pad| < n
    p = (p < 0) ? -p : p;
    p = (p >= n) ? (2 * n - 2 - p) : p;
    return p;
}

__global__ __launch_bounds__(256) void copy_x_kernel(const float* __restrict__ x,
                                                     float* __restrict__ out) {
    int t = blockIdx.x * 256 + threadIdx.x;   // NB*HWs/4 = 262144 threads
    int b = t >> 16;                          // HWs/4 = 65536 float4 per batch
    int r = t & 65535;
    const float4* src = (const float4*)(x + (size_t)b * HWs);
    float4* dst = (float4*)(out + (size_t)b * NC * HWs);
    dst[r] = src[r];
}

// Block = 256 threads = 4 rows x 256 cols output tile, 2 out channels.
// Per channel: stage the 12 needed row-segments (3 kh-groups x 4 rows,
// cols w0-DIL .. w0+255+DIL) into LDS with dense unique global loads,
// double-buffered (1 barrier/channel); serve all 36 taps from LDS at
// stride-1 (conflict-free; +-DIL pair merges into ds_read2_b32).
template <int NIN, int DIL>
__global__ __launch_bounds__(256) void msd_layer(const float* __restrict__ wts,
                                                 const float* __restrict__ bias,
                                                 float* __restrict__ buf,
                                                 int layer) {
    constexpr int SEG = 256 + 2 * DIL;          // staged row length (floats)
    constexpr int TOT = 12 * SEG;
    constexpr int NSTG = (TOT + 255) / 256;     // staging iters per thread

    __shared__ float lds[2][TOT];

    const int tid = threadIdx.x;
    const int blk = blockIdx.x;
    const int w0 = (blk & 1) << 8;              // column-half base
    const int strip = blk >> 1;                 // 0..511
    const int b = strip >> 7;
    const int h = (strip & 127) << 2;           // output rows h..h+3

    const float* base = buf + (size_t)b * NC * HWs;

    // Per-thread global source offsets for staging (constant across channels)
    int gsrc[NSTG];
#pragma unroll
    for (int k = 0; k < NSTG; ++k) {
        int u = tid + (k << 8);
        if (u > TOT - 1) u = TOT - 1;           // tail lanes: duplicate write, benign
        int r = u / SEG;
        int col = u - r * SEG;
        int kh = (r >> 2) - 1;                  // -1,0,1
        int j = r & 3;
        gsrc[k] = refl(h + j + kh * DIL, HH) * WW + refl(w0 - DIL + col, WW);
    }

    // Stage channel 0
    {
        const float* plane = base;
#pragma unroll
        for (int k = 0; k < NSTG; ++k) {
            int u = tid + (k << 8);
            if (u > TOT - 1) u = TOT - 1;
            lds[0][u] = plane[gsrc[k]];
        }
    }
    __syncthreads();

    const float b0 = bias[2 * layer];
    const float b1 = bias[2 * layer + 1];
    float a0[4] = {b0, b0, b0, b0};
    float a1[4] = {b1, b1, b1, b1};

    for (int c = 0; c < NIN; ++c) {
        const int cur = c & 1;
        if (c + 1 < NIN) {
            const float* plane = base + (size_t)(c + 1) * HWs;
            float* dstb = lds[cur ^ 1];
#pragma unroll
            for (int k = 0; k < NSTG; ++k) {
                int u = tid + (k << 8);
                if (u > TOT - 1) u = TOT - 1;
                dstb[u] = plane[gsrc[k]];
            }
        }
        const float* __restrict__ wp0 = wts + c * 9;
        const float* __restrict__ wp1 = wts + (NIN + c) * 9;
        const float* L = lds[cur];
#pragma unroll
        for (int kh = 0; kh < 3; ++kh) {
#pragma unroll
            for (int j = 0; j < 4; ++j) {
                const float* row = L + (kh * 4 + j) * SEG + tid;
                float vm = row[0];
                float vc = row[DIL];
                float vp = row[2 * DIL];
                a0[j] = fmaf(vm, wp0[kh * 3 + 0], a0[j]);
                a0[j] = fmaf(vc, wp0[kh * 3 + 1], a0[j]);
                a0[j] = fmaf(vp, wp0[kh * 3 + 2], a0[j]);
                a1[j] = fmaf(vm, wp1[kh * 3 + 0], a1[j]);
                a1[j] = fmaf(vc, wp1[kh * 3 + 1], a1[j]);
                a1[j] = fmaf(vp, wp1[kh * 3 + 2], a1[j]);
            }
        }
        __syncthreads();
    }

    float* out0 = buf + ((size_t)(b * NC + NIN)) * HWs;
    float* out1 = buf + ((size_t)(b * NC + NIN + 1)) * HWs;
#pragma unroll
    for (int j = 0; j < 4; ++j) {
        size_t opix = (size_t)(h + j) * WW + (size_t)(w0 + tid);
        out0[opix] = fmaxf(a0[j], 0.f);
        out1[opix] = fmaxf(a1[j], 0.f);
    }
}

extern "C" void kernel_launch(void* const* d_in, const int* in_sizes, int n_in,
                              void* d_out, int out_size, void* d_ws, size_t ws_size,
                              hipStream_t stream) {
    const float* x = (const float*)d_in[0];
    const float* bias = (const float*)d_in[1];
    float* out = (float*)d_out;

    const int blocks = (NB * HWs / 4) / 256;  // 1024

    copy_x_kernel<<<blocks, 256, 0, stream>>>(x, out);

#define LAYER(i, nin, dil) \
    msd_layer<nin, dil><<<blocks, 256, 0, stream>>>((const float*)d_in[2 + i], bias, out, i)

    LAYER(0, 1, 1);
    LAYER(1, 3, 2);
    LAYER(2, 5, 3);
    LAYER(3, 7, 4);
    LAYER(4, 9, 5);
    LAYER(5, 11, 6);
    LAYER(6, 13, 7);
    LAYER(7, 15, 8);
    LAYER(8, 17, 9);
    LAYER(9, 19, 10);
    LAYER(10, 21, 11);
    LAYER(11, 23, 12);
#undef LAYER
}